// Round 11
// baseline (587.452 us; speedup 1.0000x reference)
//
#include <hip/hip_runtime.h>

// ResidualSimVQ eval forward — R11: R10 + packed-f32 (v_pk_fma_f32) diet.
// Structure identical to R10 (barrier-free 9-stage loop, 4 rows/wave,
// launch_bounds(256,2), global L1-resident padded f32 Wn, LDS z-transpose).
// Packing: phases 1/2/3 use 2-wide ext-vector f32 FMA; operand pairs come
// free from dwordx4 loads (consecutive VGPRs) and packed pf2 accumulators.
// Numerics: phase-1 packing bit-identical (per-component accumulators);
// phase-2/3 even/odd-split reordering ~1e-6 — fallback-protected (GAPTHR
// 0.015) / same class as accepted f32-Wn noise. pz/A/C/commit bit-identical
// to R10. Fallback: exact f64 re-derivation from the f64 Wn table.
// commit is wave-uniform -> lane 0's copy IS the wave total (no reduction).
// Empirical law: VGPR cap = 256/min_waves -> only arg 2 (cap 128) fits this
// state (R8: 84 spills; R9: 64 spills). WRITE_SIZE ~67 MB is the no-spill
// health metric.

#define NB  16
#define DD  512
#define TT  2048
#define NCB 9
#define CS  1024
#define CD  8
#define KK  9    // CD + 1: slot 8 is the bias b
#define KP  12   // padded f32 row stride (48 B, 16B-aligned rows)
#define NBLK (NB * (TT / 16))   // 2048 k_main blocks
#define GAPTHR 0.015f

#define WS_WN_OFF  65536                                 // f64 [Wn|b], d-major [i][d][9] (fallback)
#define WS_WNF_OFF (WS_WN_OFF  + (size_t)NCB*DD*KK*8)    // f32 [Wn|b,pad], [i][d][12]
#define WS_Q_OFF   (WS_WNF_OFF + (size_t)NCB*DD*KP*4)    // f64 ||implicit||^2
#define WS_QF_OFF  (WS_Q_OFF   + (size_t)NCB*CS*8)       // f32 0.5*||implicit||^2

typedef float v2f __attribute__((ext_vector_type(2)));
typedef float v4f __attribute__((ext_vector_type(4)));
#define FMA2(a, b, c) __builtin_elementwise_fma((a), (b), (c))
#define LO(v) __builtin_shufflevector((v), (v), 0, 1)
#define HI(v) __builtin_shufflevector((v), (v), 2, 3)

__global__ void k_wn(const float* __restrict__ V, const float* __restrict__ g,
                     const float* __restrict__ bp, double* __restrict__ wn,
                     float* __restrict__ wnf) {
  int gid = blockIdx.x * 256 + threadIdx.x;
  if (gid >= NCB * DD) return;
  int i = gid / DD, d = gid % DD;
  const float* vp = V + (size_t)gid * CD;
  double v[CD], s = 0.0;
#pragma unroll
  for (int k = 0; k < CD; k++) { v[k] = (double)vp[k]; s = fma(v[k], v[k], s); }
  double den = fmax(sqrt(s), 1e-12);
  double gg = (double)g[gid];
  double* row = wn + ((size_t)i * DD + d) * KK;
  float* frow = wnf + ((size_t)i * DD + d) * KP;
#pragma unroll
  for (int k = 0; k < CD; k++) {
    double wv = gg * v[k] / den;
    row[k] = wv;
    frow[k] = (float)wv;
  }
  row[CD] = (double)bp[gid];
  frow[CD] = bp[gid];
  frow[9] = 0.0f; frow[10] = 0.0f; frow[11] = 0.0f;
}

__global__ void k_q(const float* __restrict__ CBp, const float* __restrict__ bp,
                    const double* __restrict__ wn,
                    double* __restrict__ q, float* __restrict__ qf) {
  int wid = blockIdx.x * 4 + (threadIdx.x >> 6);
  int lane = threadIdx.x & 63;
  int i = wid / CS, c = wid % CS;
  const float* cb = CBp + (size_t)(i * CS + c) * CD;
  double cbv[CD];
#pragma unroll
  for (int k = 0; k < CD; k++) cbv[k] = (double)cb[k];
  const double* wnp = wn + (size_t)i * DD * KK;
  const float* bb = bp + (size_t)i * DD;
  double acc = 0.0;
#pragma unroll
  for (int j = 0; j < 8; j++) {
    int d = j * 64 + lane;
    double imp = (double)bb[d];
#pragma unroll
    for (int k = 0; k < CD; k++) imp = fma(cbv[k], wnp[(size_t)d * KK + k], imp);
    acc = fma(imp, imp, acc);
  }
#pragma unroll
  for (int o = 32; o; o >>= 1) acc += __shfl_xor(acc, o, 64);
  if (lane == 0) { q[wid] = acc; qf[wid] = (float)(0.5 * acc); }
}

__launch_bounds__(256, 2)
__global__ void k_main(const float* __restrict__ z, const float* __restrict__ CBp,
                       const double* __restrict__ wn, const float* __restrict__ wnf,
                       const double* __restrict__ qtab, const float* __restrict__ qftab,
                       float* __restrict__ out_zq, float* __restrict__ out_codes,
                       double* __restrict__ partials) {
  __shared__ __align__(16) float tile[DD * 17];   // 34816 B
  __shared__ double cbuf[4];

  const int tid = threadIdx.x, lane = tid & 63, w = tid >> 6;
  const int bb = blockIdx.x >> 7, tg = blockIdx.x & 127;
  const int t0 = tg * 16;
  const float* zb = z + (size_t)bb * DD * TT + t0;

  // ---- prologue: stage z[b,:,t0:t0+16] coalesced, transpose in LDS ----
#pragma unroll
  for (int m = 0; m < 8; m++) {
    int F = tid + m * 256, d = F >> 2, qq = F & 3;
    const float4 v = *(const float4*)(zb + (size_t)d * TT + qq * 4);
    tile[d * 17 + qq * 4 + 0] = v.x; tile[d * 17 + qq * 4 + 1] = v.y;
    tile[d * 17 + qq * 4 + 2] = v.z; tile[d * 17 + qq * 4 + 3] = v.w;
  }
  __syncthreads();

  double res[4][8], ns2[4];
#pragma unroll
  for (int r = 0; r < 4; r++) {
    double s = 0.0;
#pragma unroll
    for (int j = 0; j < 8; j++) {
      res[r][j] = (double)tile[(j * 64 + lane) * 17 + (w * 4 + r)];
      s = fma(res[r][j], res[r][j], s);
    }
    ns2[r] = s;
  }
#pragma unroll
  for (int o = 32; o; o >>= 1)
#pragma unroll
    for (int r = 0; r < 4; r++) ns2[r] += __shfl_xor(ns2[r], o, 64);

  double commit = 0.0;

  for (int i = 0; i < NCB; i++) {
    const float* wfp = wnf + (size_t)i * DD * KP;
    const float* cbbase = CBp + (size_t)i * CS * CD;
    const float* qfb = qftab + i * CS;
    const double* qb = qtab + i * CS;

    // ---- phase 1: pf2[r][kk] = -(res . Wn) packed pairs; pf8 = -(res.b) ----
    v2f pf2[4][4];
    float pf8[4];
    const v2f z2 = {0.0f, 0.0f};
#pragma unroll
    for (int r = 0; r < 4; r++) {
#pragma unroll
      for (int kk = 0; kk < 4; kk++) pf2[r][kk] = z2;
      pf8[r] = 0.0f;
    }
#pragma unroll
    for (int j = 0; j < 8; j++) {
      const float* row = wfp + (size_t)(j * 64 + lane) * KP;
      const v4f w04 = *(const v4f*)(row);
      const v4f w44 = *(const v4f*)(row + 4);
      const float w8 = row[8];
      const v2f wA = LO(w04), wB = HI(w04), wC = LO(w44), wD = HI(w44);
#pragma unroll
      for (int r = 0; r < 4; r++) {
        float rv = -(float)res[r][j];
        v2f rv2 = {rv, rv};
        pf2[r][0] = FMA2(rv2, wA, pf2[r][0]);
        pf2[r][1] = FMA2(rv2, wB, pf2[r][1]);
        pf2[r][2] = FMA2(rv2, wC, pf2[r][2]);
        pf2[r][3] = FMA2(rv2, wD, pf2[r][3]);
        pf8[r] = fmaf(rv, w8, pf8[r]);
      }
    }
    // cross-lane reduce: packed adds (bit-identical per component)
#pragma unroll
    for (int o = 32; o; o >>= 1) {
#pragma unroll
      for (int r = 0; r < 4; r++) {
#pragma unroll
        for (int kk = 0; kk < 4; kk++) {
          double dv = __builtin_bit_cast(double, pf2[r][kk]);
          dv = __shfl_xor(dv, o, 64);
          pf2[r][kk] += __builtin_bit_cast(v2f, dv);
        }
        pf8[r] += __shfl_xor(pf8[r], o, 64);
      }
    }

    // ---- phase 2: f32 argmin, one CB sweep, packed scoring, split chains ----
    float s1a[4], s2a[4], s1b[4], s2b[4];
    int   c1a[4], c1b[4];
#pragma unroll
    for (int r = 0; r < 4; r++) {
      s1a[r] = s2a[r] = s1b[r] = s2b[r] = 3.4e38f;
      c1a[r] = c1b[r] = 0;
    }
#pragma unroll 4
    for (int m = 0; m < 16; m += 2) {
#pragma unroll
      for (int h = 0; h < 2; h++) {
        int c = (m + h) * 64 + lane;
        const v4f q0 = *(const v4f*)(cbbase + (size_t)c * CD);
        const v4f q1 = *(const v4f*)(cbbase + (size_t)c * CD + 4);
        const float qv = qfb[c];
        const v2f cA = LO(q0), cB = HI(q0), cC = LO(q1), cD = HI(q1);
#pragma unroll
        for (int r = 0; r < 4; r++) {
          v2f acc = cA * pf2[r][0];
          acc = FMA2(cB, pf2[r][1], acc);
          acc = FMA2(cC, pf2[r][2], acc);
          acc = FMA2(cD, pf2[r][3], acc);
          float s = (qv + acc.x) + acc.y;
          if (h == 0) {
            if (s < s1a[r]) { s2a[r] = s1a[r]; s1a[r] = s; c1a[r] = c; }
            else            { s2a[r] = fminf(s2a[r], s); }
          } else {
            if (s < s1b[r]) { s2b[r] = s1b[r]; s1b[r] = s; c1b[r] = c; }
            else            { s2b[r] = fminf(s2b[r], s); }
          }
        }
      }
    }
    float s1[4], s2[4]; int c1[4];
#pragma unroll
    for (int r = 0; r < 4; r++) {
      if (s1a[r] < s1b[r] || (s1a[r] == s1b[r] && c1a[r] < c1b[r])) {
        s1[r] = s1a[r]; c1[r] = c1a[r]; s2[r] = fminf(s2a[r], s1b[r]);
      } else {
        s1[r] = s1b[r]; c1[r] = c1b[r]; s2[r] = fminf(s2b[r], s1a[r]);
      }
    }
#pragma unroll
    for (int o = 32; o; o >>= 1) {
#pragma unroll
      for (int r = 0; r < 4; r++) {
        float os1 = __shfl_xor(s1[r], o, 64);
        int   oc1 = __shfl_xor(c1[r], o, 64);
        float os2 = __shfl_xor(s2[r], o, 64);
        float hi = fmaxf(s1[r], os1);
        s2[r] = fminf(fminf(s2[r], os2), hi);
        if (os1 < s1[r] || (os1 == s1[r] && oc1 < c1[r])) { s1[r] = os1; c1[r] = oc1; }
      }
    }

    // ---- per-row: rare exact-f64 fallback (global f64 Wn), scalars ----
    double Ap[4], Cm[4];
    v2f cbf2[4][4];
#pragma unroll
    for (int r = 0; r < 4; r++) {
      if (s2[r] - s1[r] < GAPTHR) {   // wave-uniform, rare
        double pd[KK];
#pragma unroll
        for (int k = 0; k < KK; k++) pd[k] = 0.0;
#pragma unroll
        for (int j = 0; j < 8; j++) {
          const double* wrow = wn + ((size_t)i * DD + j * 64 + lane) * KK;
          double rv = res[r][j];
#pragma unroll
          for (int k = 0; k < KK; k++) pd[k] = fma(rv, wrow[k], pd[k]);
        }
#pragma unroll
        for (int o = 32; o; o >>= 1)
#pragma unroll
          for (int k = 0; k < KK; k++) pd[k] += __shfl_xor(pd[k], o, 64);
        double pm2[8];
#pragma unroll
        for (int k = 0; k < 8; k++) pm2[k] = -2.0 * pd[k];
        double bs = 1e300; int bc = 0;
#pragma unroll 4
        for (int m = 0; m < 16; m++) {
          int c = m * 64 + lane;
          const float* cb2 = cbbase + (size_t)c * CD;
          double s = qb[c];
#pragma unroll
          for (int k = 0; k < 8; k++) s = fma((double)cb2[k], pm2[k], s);
          if (s < bs) { bs = s; bc = c; }
        }
#pragma unroll
        for (int o = 32; o; o >>= 1) {
          double obs = __shfl_xor(bs, o, 64);
          int    obc = __shfl_xor(bc, o, 64);
          if (obs < bs || (obs == bs && obc < bc)) { bs = obs; bc = obc; }
        }
        c1[r] = bc;
      }
      int cu = __builtin_amdgcn_readfirstlane(c1[r]);
      const float* cbr = cbbase + (size_t)cu * CD;
      // pz in f64 from packed pf components, k-ascending (bit-identical R10)
      double pzn = (double)pf8[r];
#pragma unroll
      for (int kk = 0; kk < 4; kk++) {
        float clo = cbr[2 * kk], chi = cbr[2 * kk + 1];
        v2f cc = {clo, chi};
        cbf2[r][kk] = cc;
        pzn = fma((double)clo, (double)pf2[r][kk].x, pzn);
        pzn = fma((double)chi, (double)pf2[r][kk].y, pzn);
      }
      double pz = -pzn;
      double nt2 = qb[cu];
      double n2 = ns2[r];
      double rns = (n2  > 1e-12) ? rsqrt(n2)  : 1e6;
      double rnt = (nt2 > 1e-12) ? rsqrt(nt2) : 1e6;
      double s_nt = nt2 * rnt;                // sqrt(nt2)
      double wn2 = n2 * rns * rns + 2.0 * pz * rns * rnt + nt2 * rnt * rnt;
      double rdwn = (wn2 > 1e-12) ? rsqrt(wn2) : 1e6;
      double eu = n2 * rns;
      double ew = (n2 * rns + pz * rnt) * rdwn;
      double scale = s_nt * rns;
      double A = scale * (1.0 - 2.0 * ew * rdwn * rns);
      double C = scale * rnt * 2.0 * (eu - ew * rdwn);
      commit += n2 - 2.0 * pz + nt2;
      double ap = 1.0 - A;
      Ap[r] = ap; Cm[r] = C;
      ns2[r] = ap * ap * n2 - 2.0 * ap * C * pz + C * C * nt2;
      if (lane == 0)
        out_codes[((size_t)bb * NCB + i) * TT + t0 + w * 4 + r] = (float)cu;
    }

    // ---- phase 3: res' = Ap*res - Cm*(b + Wn.cb), packed imp, one pass ----
#pragma unroll
    for (int j = 0; j < 8; j++) {
      const float* row = wfp + (size_t)(j * 64 + lane) * KP;
      const v4f w04 = *(const v4f*)(row);
      const v4f w44 = *(const v4f*)(row + 4);
      const float w8 = row[8];
      const v2f wA = LO(w04), wB = HI(w04), wC = LO(w44), wD = HI(w44);
#pragma unroll
      for (int r = 0; r < 4; r++) {
        v2f acc = cbf2[r][0] * wA;
        acc = FMA2(cbf2[r][1], wB, acc);
        acc = FMA2(cbf2[r][2], wC, acc);
        acc = FMA2(cbf2[r][3], wD, acc);
        float impf = (w8 + acc.x) + acc.y;
        res[r][j] = Ap[r] * res[r][j] - Cm[r] * (double)impf;
      }
    }
  }

  // ---- commit: wave-uniform already; lane 0 holds the wave total ----
  if (lane == 0) cbuf[w] = commit;

  // ---- z_q = z - res_final : transpose via LDS, store coalesced ----
  __syncthreads();   // all waves done before tile reuse
#pragma unroll
  for (int r = 0; r < 4; r++)
#pragma unroll
    for (int j = 0; j < 8; j++)
      tile[(j * 64 + lane) * 17 + (w * 4 + r)] = (float)res[r][j];
  __syncthreads();   // covers cbuf too
#pragma unroll
  for (int m = 0; m < 8; m++) {
    int F = tid + m * 256, d = F >> 2, qq = F & 3;
    const float4 v = *(const float4*)(zb + (size_t)d * TT + qq * 4);
    float4 o;
    o.x = v.x - tile[d * 17 + qq * 4 + 0];
    o.y = v.y - tile[d * 17 + qq * 4 + 1];
    o.z = v.z - tile[d * 17 + qq * 4 + 2];
    o.w = v.w - tile[d * 17 + qq * 4 + 3];
    *(float4*)(out_zq + ((size_t)bb * DD + d) * TT + t0 + qq * 4) = o;
  }
  if (tid == 0)
    partials[blockIdx.x] = cbuf[0] + cbuf[1] + cbuf[2] + cbuf[3];
}

__global__ void k_fin(const double* __restrict__ partials, float* __restrict__ outc) {
  __shared__ double sb[4];
  int tid = threadIdx.x, lane = tid & 63, w = tid >> 6;
  double s = 0.0;
#pragma unroll
  for (int m = 0; m < NBLK / 256; m++) s += partials[tid + m * 256];
#pragma unroll
  for (int o = 32; o; o >>= 1) s += __shfl_xor(s, o, 64);
  if (lane == 0) sb[w] = s;
  __syncthreads();
  if (tid == 0) {
    double tot = sb[0] + sb[1] + sb[2] + sb[3];
    outc[0] = (float)(tot * 1.25 / (double)((size_t)NB * TT * DD));
  }
}

extern "C" void kernel_launch(void* const* d_in, const int* in_sizes, int n_in,
                              void* d_out, int out_size, void* d_ws, size_t ws_size,
                              hipStream_t stream) {
  const float* z  = (const float*)d_in[0];
  const float* V  = (const float*)d_in[1];
  const float* g  = (const float*)d_in[2];
  const float* b  = (const float*)d_in[3];
  const float* CB = (const float*)d_in[4];
  float* out = (float*)d_out;

  double* parts = (double*)d_ws;
  double* wn  = (double*)((char*)d_ws + WS_WN_OFF);
  float*  wnf = (float*)((char*)d_ws + WS_WNF_OFF);
  double* q   = (double*)((char*)d_ws + WS_Q_OFF);
  float*  qf  = (float*)((char*)d_ws + WS_QF_OFF);

  hipLaunchKernelGGL(k_wn, dim3((NCB * DD + 255) / 256), dim3(256), 0, stream,
                     V, g, b, wn, wnf);
  hipLaunchKernelGGL(k_q, dim3((NCB * CS) / 4), dim3(256), 0, stream, CB, b, wn, q, qf);
  hipLaunchKernelGGL(k_main, dim3(NBLK), dim3(256), 0, stream,
                     z, CB, wn, wnf, q, qf,
                     out, out + (size_t)NB * DD * TT, parts);
  hipLaunchKernelGGL(k_fin, dim3(1), dim3(256), 0, stream,
                     parts, out + (size_t)NB * DD * TT + (size_t)NB * NCB * TT);
}

// Round 13
// 530.546 us; speedup vs baseline: 1.1073x; 1.1073x over previous
//
#include <hip/hip_runtime.h>

// ResidualSimVQ eval forward — R13: R12 intent with the compile fix (clang
// ext_vector float4 for __builtin_nontemporal_*; HIP_vector_type is a struct
// the builtin rejects).  R10 (best, 538us) + non-temporal hints on streaming
// z/output traffic (keep the ~60 KB/stage table working set L1-resident) +
// f32 rotation-scalar chains (guarded rsqrtf; A/C need only ~1e-7 rel —
// decisions are made before the scalars, fallback margin 1000x).
// Structure identical to R10: barrier-free 9-stage loop, 4 rows/wave,
// launch_bounds(256,2) (VGPR cap law: 256/min_waves; only arg 2 fits this
// state), global L1-resident padded f32 Wn, LDS z-transpose, exact-f64
// fallback for gap < 0.015.  R11 lesson: v_pk packing cut VALU busy but
// added stall — reverted.
// commit is wave-uniform -> lane 0's copy IS the wave total (no reduction).
// WRITE_SIZE ~67 MB is the no-spill health metric.

#define NB  16
#define DD  512
#define TT  2048
#define NCB 9
#define CS  1024
#define CD  8
#define KK  9    // CD + 1: slot 8 is the bias b
#define KP  12   // padded f32 row stride (48 B, 16B-aligned rows)
#define NBLK (NB * (TT / 16))   // 2048 k_main blocks
#define GAPTHR 0.015f

#define WS_WN_OFF  65536                                 // f64 [Wn|b], d-major [i][d][9] (fallback)
#define WS_WNF_OFF (WS_WN_OFF  + (size_t)NCB*DD*KK*8)    // f32 [Wn|b,pad], [i][d][12]
#define WS_Q_OFF   (WS_WNF_OFF + (size_t)NCB*DD*KP*4)    // f64 ||implicit||^2
#define WS_QF_OFF  (WS_Q_OFF   + (size_t)NCB*CS*8)       // f32 0.5*||implicit||^2

typedef float vf4 __attribute__((ext_vector_type(4)));   // clang vector: ok for nontemporal builtins

__global__ void k_wn(const float* __restrict__ V, const float* __restrict__ g,
                     const float* __restrict__ bp, double* __restrict__ wn,
                     float* __restrict__ wnf) {
  int gid = blockIdx.x * 256 + threadIdx.x;
  if (gid >= NCB * DD) return;
  int i = gid / DD, d = gid % DD;
  const float* vp = V + (size_t)gid * CD;
  double v[CD], s = 0.0;
#pragma unroll
  for (int k = 0; k < CD; k++) { v[k] = (double)vp[k]; s = fma(v[k], v[k], s); }
  double den = fmax(sqrt(s), 1e-12);
  double gg = (double)g[gid];
  double* row = wn + ((size_t)i * DD + d) * KK;
  float* frow = wnf + ((size_t)i * DD + d) * KP;
#pragma unroll
  for (int k = 0; k < CD; k++) {
    double wv = gg * v[k] / den;
    row[k] = wv;
    frow[k] = (float)wv;
  }
  row[CD] = (double)bp[gid];
  frow[CD] = bp[gid];
  frow[9] = 0.0f; frow[10] = 0.0f; frow[11] = 0.0f;
}

__global__ void k_q(const float* __restrict__ CBp, const float* __restrict__ bp,
                    const double* __restrict__ wn,
                    double* __restrict__ q, float* __restrict__ qf) {
  int wid = blockIdx.x * 4 + (threadIdx.x >> 6);
  int lane = threadIdx.x & 63;
  int i = wid / CS, c = wid % CS;
  const float* cb = CBp + (size_t)(i * CS + c) * CD;
  double cbv[CD];
#pragma unroll
  for (int k = 0; k < CD; k++) cbv[k] = (double)cb[k];
  const double* wnp = wn + (size_t)i * DD * KK;
  const float* bb = bp + (size_t)i * DD;
  double acc = 0.0;
#pragma unroll
  for (int j = 0; j < 8; j++) {
    int d = j * 64 + lane;
    double imp = (double)bb[d];
#pragma unroll
    for (int k = 0; k < CD; k++) imp = fma(cbv[k], wnp[(size_t)d * KK + k], imp);
    acc = fma(imp, imp, acc);
  }
#pragma unroll
  for (int o = 32; o; o >>= 1) acc += __shfl_xor(acc, o, 64);
  if (lane == 0) { q[wid] = acc; qf[wid] = (float)(0.5 * acc); }
}

__launch_bounds__(256, 2)
__global__ void k_main(const float* __restrict__ z, const float* __restrict__ CBp,
                       const double* __restrict__ wn, const float* __restrict__ wnf,
                       const double* __restrict__ qtab, const float* __restrict__ qftab,
                       float* __restrict__ out_zq, float* __restrict__ out_codes,
                       double* __restrict__ partials) {
  __shared__ __align__(16) float tile[DD * 17];   // 34816 B
  __shared__ double cbuf[4];

  const int tid = threadIdx.x, lane = tid & 63, w = tid >> 6;
  const int bb = blockIdx.x >> 7, tg = blockIdx.x & 127;
  const int t0 = tg * 16;
  const float* zb = z + (size_t)bb * DD * TT + t0;

  // ---- prologue: stage z (non-temporal: zero L1 reuse), transpose in LDS ----
#pragma unroll
  for (int m = 0; m < 8; m++) {
    int F = tid + m * 256, d = F >> 2, qq = F & 3;
    const vf4 v = __builtin_nontemporal_load((const vf4*)(zb + (size_t)d * TT + qq * 4));
    tile[d * 17 + qq * 4 + 0] = v.x; tile[d * 17 + qq * 4 + 1] = v.y;
    tile[d * 17 + qq * 4 + 2] = v.z; tile[d * 17 + qq * 4 + 3] = v.w;
  }
  __syncthreads();

  double res[4][8], ns2[4];
#pragma unroll
  for (int r = 0; r < 4; r++) {
    double s = 0.0;
#pragma unroll
    for (int j = 0; j < 8; j++) {
      res[r][j] = (double)tile[(j * 64 + lane) * 17 + (w * 4 + r)];
      s = fma(res[r][j], res[r][j], s);
    }
    ns2[r] = s;
  }
#pragma unroll
  for (int o = 32; o; o >>= 1)
#pragma unroll
    for (int r = 0; r < 4; r++) ns2[r] += __shfl_xor(ns2[r], o, 64);

  double commit = 0.0;

  for (int i = 0; i < NCB; i++) {
    const float* wfp = wnf + (size_t)i * DD * KP;
    const float* cbbase = CBp + (size_t)i * CS * CD;
    const float* qfb = qftab + i * CS;
    const double* qb = qtab + i * CS;

    // ---- phase 1: pf[r][k] = -(res . [Wn|b]) in f32, one pass, 4 rows ----
    float pf[4][KK];
#pragma unroll
    for (int r = 0; r < 4; r++)
#pragma unroll
      for (int k = 0; k < KK; k++) pf[r][k] = 0.0f;
#pragma unroll
    for (int j = 0; j < 8; j++) {
      const float* row = wfp + (size_t)(j * 64 + lane) * KP;
      const float4 w0 = *(const float4*)(row);
      const float4 w1 = *(const float4*)(row + 4);
      const float  w8 = row[8];
      float rv[4];
#pragma unroll
      for (int r = 0; r < 4; r++) rv[r] = -(float)res[r][j];
#pragma unroll
      for (int r = 0; r < 4; r++) {
        pf[r][0] = fmaf(rv[r], w0.x, pf[r][0]);
        pf[r][1] = fmaf(rv[r], w0.y, pf[r][1]);
        pf[r][2] = fmaf(rv[r], w0.z, pf[r][2]);
        pf[r][3] = fmaf(rv[r], w0.w, pf[r][3]);
        pf[r][4] = fmaf(rv[r], w1.x, pf[r][4]);
        pf[r][5] = fmaf(rv[r], w1.y, pf[r][5]);
        pf[r][6] = fmaf(rv[r], w1.z, pf[r][6]);
        pf[r][7] = fmaf(rv[r], w1.w, pf[r][7]);
        pf[r][8] = fmaf(rv[r], w8,   pf[r][8]);
      }
    }
#pragma unroll
    for (int o = 32; o; o >>= 1)
#pragma unroll
      for (int r = 0; r < 4; r++)
#pragma unroll
        for (int k = 0; k < KK; k++) pf[r][k] += __shfl_xor(pf[r][k], o, 64);

    // ---- phase 2: f32 argmin, one CB sweep, split even/odd chains ----
    float s1a[4], s2a[4], s1b[4], s2b[4];
    int   c1a[4], c1b[4];
#pragma unroll
    for (int r = 0; r < 4; r++) {
      s1a[r] = s2a[r] = s1b[r] = s2b[r] = 3.4e38f;
      c1a[r] = c1b[r] = 0;
    }
#pragma unroll 4
    for (int m = 0; m < 16; m += 2) {
#pragma unroll
      for (int h = 0; h < 2; h++) {
        int c = (m + h) * 64 + lane;
        const float4 c0 = *(const float4*)(cbbase + (size_t)c * CD);
        const float4 cx = *(const float4*)(cbbase + (size_t)c * CD + 4);
        float qv = qfb[c];
#pragma unroll
        for (int r = 0; r < 4; r++) {
          float s = qv;
          s = fmaf(c0.x, pf[r][0], s); s = fmaf(c0.y, pf[r][1], s);
          s = fmaf(c0.z, pf[r][2], s); s = fmaf(c0.w, pf[r][3], s);
          s = fmaf(cx.x, pf[r][4], s); s = fmaf(cx.y, pf[r][5], s);
          s = fmaf(cx.z, pf[r][6], s); s = fmaf(cx.w, pf[r][7], s);
          if (h == 0) {
            if (s < s1a[r]) { s2a[r] = s1a[r]; s1a[r] = s; c1a[r] = c; }
            else            { s2a[r] = fminf(s2a[r], s); }
          } else {
            if (s < s1b[r]) { s2b[r] = s1b[r]; s1b[r] = s; c1b[r] = c; }
            else            { s2b[r] = fminf(s2b[r], s); }
          }
        }
      }
    }
    float s1[4], s2[4]; int c1[4];
#pragma unroll
    for (int r = 0; r < 4; r++) {
      if (s1a[r] < s1b[r] || (s1a[r] == s1b[r] && c1a[r] < c1b[r])) {
        s1[r] = s1a[r]; c1[r] = c1a[r]; s2[r] = fminf(s2a[r], s1b[r]);
      } else {
        s1[r] = s1b[r]; c1[r] = c1b[r]; s2[r] = fminf(s2b[r], s1a[r]);
      }
    }
#pragma unroll
    for (int o = 32; o; o >>= 1) {
#pragma unroll
      for (int r = 0; r < 4; r++) {
        float os1 = __shfl_xor(s1[r], o, 64);
        int   oc1 = __shfl_xor(c1[r], o, 64);
        float os2 = __shfl_xor(s2[r], o, 64);
        float hi = fmaxf(s1[r], os1);
        s2[r] = fminf(fminf(s2[r], os2), hi);
        if (os1 < s1[r] || (os1 == s1[r] && oc1 < c1[r])) { s1[r] = os1; c1[r] = oc1; }
      }
    }

    // ---- per-row: rare exact-f64 fallback (global f64 Wn), scalars ----
    double Ap[4], Cm[4];
    float cbf[4][8];
#pragma unroll
    for (int r = 0; r < 4; r++) {
      if (s2[r] - s1[r] < GAPTHR) {   // wave-uniform, rare
        double pd[KK];
#pragma unroll
        for (int k = 0; k < KK; k++) pd[k] = 0.0;
#pragma unroll
        for (int j = 0; j < 8; j++) {
          const double* wrow = wn + ((size_t)i * DD + j * 64 + lane) * KK;
          double rv = res[r][j];
#pragma unroll
          for (int k = 0; k < KK; k++) pd[k] = fma(rv, wrow[k], pd[k]);
        }
#pragma unroll
        for (int o = 32; o; o >>= 1)
#pragma unroll
          for (int k = 0; k < KK; k++) pd[k] += __shfl_xor(pd[k], o, 64);
        double pm2[8];
#pragma unroll
        for (int k = 0; k < 8; k++) pm2[k] = -2.0 * pd[k];
        double bs = 1e300; int bc = 0;
#pragma unroll 4
        for (int m = 0; m < 16; m++) {
          int c = m * 64 + lane;
          const float* cb2 = cbbase + (size_t)c * CD;
          double s = qb[c];
#pragma unroll
          for (int k = 0; k < 8; k++) s = fma((double)cb2[k], pm2[k], s);
          if (s < bs) { bs = s; bc = c; }
        }
#pragma unroll
        for (int o = 32; o; o >>= 1) {
          double obs = __shfl_xor(bs, o, 64);
          int    obc = __shfl_xor(bc, o, 64);
          if (obs < bs || (obs == bs && obc < bc)) { bs = obs; bc = obc; }
        }
        c1[r] = bc;
      }
      int cu = __builtin_amdgcn_readfirstlane(c1[r]);
      const float* cbr = cbbase + (size_t)cu * CD;
      double pzn = (double)pf[r][8];
#pragma unroll
      for (int k = 0; k < 8; k++) {
        float cf = cbr[k];
        cbf[r][k] = cf;
        pzn = fma((double)cf, (double)pf[r][k], pzn);
      }
      double pz = -pzn;
      double nt2 = qb[cu];
      double n2 = ns2[r];
      // rotation scalars in f32 (A/C need only ~1e-7 rel; decisions already made)
      float n2f = (float)n2, nt2f = (float)nt2, pzf = (float)pz;
      float rnsf = (n2f  > 1e-12f) ? rsqrtf(n2f)  : 1e6f;
      float rntf = (nt2f > 1e-12f) ? rsqrtf(nt2f) : 1e6f;
      float sntf = nt2f * rntf;               // sqrt(nt2)
      float wn2f = n2f * rnsf * rnsf + 2.0f * pzf * rnsf * rntf + nt2f * rntf * rntf;
      float rdwf = (wn2f > 1e-12f) ? rsqrtf(wn2f) : 1e6f;
      float euf = n2f * rnsf;
      float ewf = (n2f * rnsf + pzf * rntf) * rdwf;
      float scalef = sntf * rnsf;
      float Af = scalef * (1.0f - 2.0f * ewf * rdwf * rnsf);
      float Cf = scalef * rntf * 2.0f * (euf - ewf * rdwf);
      commit += n2 - 2.0 * pz + nt2;
      double ap = 1.0 - (double)Af;
      double C  = (double)Cf;
      Ap[r] = ap; Cm[r] = C;
      ns2[r] = ap * ap * n2 - 2.0 * ap * C * pz + C * C * nt2;
      if (lane == 0)
        out_codes[((size_t)bb * NCB + i) * TT + t0 + w * 4 + r] = (float)cu;
    }

    // ---- phase 3: res' = Ap*res - Cm*(b + Wn.cb), f32 imp, one pass ----
#pragma unroll
    for (int j = 0; j < 8; j++) {
      const float* row = wfp + (size_t)(j * 64 + lane) * KP;
      const float4 w0 = *(const float4*)(row);
      const float4 w1 = *(const float4*)(row + 4);
      const float  w8 = row[8];
#pragma unroll
      for (int r = 0; r < 4; r++) {
        float impf = w8;
        impf = fmaf(cbf[r][0], w0.x, impf);
        impf = fmaf(cbf[r][1], w0.y, impf);
        impf = fmaf(cbf[r][2], w0.z, impf);
        impf = fmaf(cbf[r][3], w0.w, impf);
        impf = fmaf(cbf[r][4], w1.x, impf);
        impf = fmaf(cbf[r][5], w1.y, impf);
        impf = fmaf(cbf[r][6], w1.z, impf);
        impf = fmaf(cbf[r][7], w1.w, impf);
        res[r][j] = Ap[r] * res[r][j] - Cm[r] * (double)impf;
      }
    }
  }

  // ---- commit: wave-uniform already; lane 0 holds the wave total ----
  if (lane == 0) cbuf[w] = commit;

  // ---- z_q = z - res_final : transpose via LDS, store coalesced (nt) ----
  __syncthreads();   // all waves done before tile reuse
#pragma unroll
  for (int r = 0; r < 4; r++)
#pragma unroll
    for (int j = 0; j < 8; j++)
      tile[(j * 64 + lane) * 17 + (w * 4 + r)] = (float)res[r][j];
  __syncthreads();   // covers cbuf too
#pragma unroll
  for (int m = 0; m < 8; m++) {
    int F = tid + m * 256, d = F >> 2, qq = F & 3;
    const vf4 v = __builtin_nontemporal_load((const vf4*)(zb + (size_t)d * TT + qq * 4));
    vf4 o;
    o.x = v.x - tile[d * 17 + qq * 4 + 0];
    o.y = v.y - tile[d * 17 + qq * 4 + 1];
    o.z = v.z - tile[d * 17 + qq * 4 + 2];
    o.w = v.w - tile[d * 17 + qq * 4 + 3];
    __builtin_nontemporal_store(o, (vf4*)(out_zq + ((size_t)bb * DD + d) * TT + t0 + qq * 4));
  }
  if (tid == 0)
    partials[blockIdx.x] = cbuf[0] + cbuf[1] + cbuf[2] + cbuf[3];
}

__global__ void k_fin(const double* __restrict__ partials, float* __restrict__ outc) {
  __shared__ double sb[4];
  int tid = threadIdx.x, lane = tid & 63, w = tid >> 6;
  double s = 0.0;
#pragma unroll
  for (int m = 0; m < NBLK / 256; m++) s += partials[tid + m * 256];
#pragma unroll
  for (int o = 32; o; o >>= 1) s += __shfl_xor(s, o, 64);
  if (lane == 0) sb[w] = s;
  __syncthreads();
  if (tid == 0) {
    double tot = sb[0] + sb[1] + sb[2] + sb[3];
    outc[0] = (float)(tot * 1.25 / (double)((size_t)NB * TT * DD));
  }
}

extern "C" void kernel_launch(void* const* d_in, const int* in_sizes, int n_in,
                              void* d_out, int out_size, void* d_ws, size_t ws_size,
                              hipStream_t stream) {
  const float* z  = (const float*)d_in[0];
  const float* V  = (const float*)d_in[1];
  const float* g  = (const float*)d_in[2];
  const float* b  = (const float*)d_in[3];
  const float* CB = (const float*)d_in[4];
  float* out = (float*)d_out;

  double* parts = (double*)d_ws;
  double* wn  = (double*)((char*)d_ws + WS_WN_OFF);
  float*  wnf = (float*)((char*)d_ws + WS_WNF_OFF);
  double* q   = (double*)((char*)d_ws + WS_Q_OFF);
  float*  qf  = (float*)((char*)d_ws + WS_QF_OFF);

  hipLaunchKernelGGL(k_wn, dim3((NCB * DD + 255) / 256), dim3(256), 0, stream,
                     V, g, b, wn, wnf);
  hipLaunchKernelGGL(k_q, dim3((NCB * CS) / 4), dim3(256), 0, stream, CB, b, wn, q, qf);
  hipLaunchKernelGGL(k_main, dim3(NBLK), dim3(256), 0, stream,
                     z, CB, wn, wnf, q, qf,
                     out, out + (size_t)NB * DD * TT, parts);
  hipLaunchKernelGGL(k_fin, dim3(1), dim3(256), 0, stream,
                     parts, out + (size_t)NB * DD * TT + (size_t)NB * NCB * TT);
}